// Round 2
// baseline (91.156 us; speedup 1.0000x reference)
//
#include <hip/hip_runtime.h>

#define EPSF 1e-6f
#define TPB 256
#define KMAX 24          // max segmentation channels supported (K=21 here)
#define CELL_MAX 448     // >= K*G upper bound (21*21=441)
#define CNT_IDX 444      // int counter slot (float index) in d_ws

// Fused: A[k,g] = sum_n d[k,n]*gi[g,n], d = log((s+eps)/(1-s+eps));
// argmin_g ce[k,g] == argmax_g A[k,g]  (ce = -(A + const_k)/N).
// Cross-block combine via device-scope float atomics; last block does argmax.
__global__ __launch_bounds__(TPB) void msk_fused(
    const float* __restrict__ seg,   // (N, K) row-major
    const int* __restrict__ gt,      // (Gmax, N) row-major
    const int* __restrict__ gpn,     // scalar gt_plane_num
    float* __restrict__ sums,        // d_ws: [CELL_MAX] float sums, int counter at CNT_IDX
    int* __restrict__ out,           // (K,) int32 argmin indices
    int N, int K, int NT, int NBLK)
{
    const int G = *gpn;
    const int KG = K * G;
    const int tid = threadIdx.x;

    __shared__ float sd[TPB * KMAX];     // seg tile, then log-odds in place
    __shared__ unsigned m_lds[TPB];
    __shared__ int last_flag;
    __shared__ float A[CELL_MAX];

    // fixed cell assignment: thread owns cells tid and tid+TPB (KG <= 2*TPB)
    const int c0 = tid;
    const int c1 = tid + TPB;
    const bool v0 = (c0 < KG);
    const bool v1 = (c1 < KG);
    const int k0 = v0 ? (c0 / G) : 0;
    const int g0 = v0 ? (c0 - k0 * G) : 0;
    const int k1 = v1 ? (c1 / G) : 0;
    const int g1 = v1 ? (c1 - k1 * G) : 0;

    float acc0 = 0.f, acc1 = 0.f;
    const long long NK = (long long)N * K;
    const int TE = TPB * K;

    for (int tile = blockIdx.x; tile < NT; tile += NBLK) {
        const long long pix0 = (long long)tile * TPB;
        const long long e0 = pix0 * K;

        // coalesced staging of the tile's seg rows (TPB*K contiguous floats)
        for (int idx = tid; idx < TE; idx += TPB) {
            const long long ge = e0 + idx;
            sd[idx] = (ge < NK) ? seg[ge] : 0.f;       // LDS write stride TPB: 2-way, free
        }

        // GT mask bits for this thread's pixel (coalesced loads per g)
        {
            const long long p = pix0 + tid;
            unsigned m = 0u;
            if (p < N) {
                for (int g = 0; g < G; ++g)
                    m |= (gt[(long long)g * N + p] != 0) ? (1u << g) : 0u;
            }
            m_lds[tid] = m;
        }
        __syncthreads();

        // in-place log-odds for own pixel (lane stride K=21, gcd(21,32)=1: conflict-free)
        if (pix0 + tid < N) {
            const int b = tid * K;
            for (int k = 0; k < K; ++k) {
                const float s = sd[b + k];
                sd[b + k] = __logf((s + EPSF) / (1.0f - s + EPSF));
            }
        }
        __syncthreads();

        // accumulate this tile into the thread's two cells
        {
            float s0 = 0.f, s1 = 0.f;
            #pragma unroll 4
            for (int t = 0; t < TPB; ++t) {
                const unsigned mm = m_lds[t];          // same-address broadcast
                s0 += ((mm >> g0) & 1u) ? sd[t * K + k0] : 0.f;  // ~4 consecutive words/wave
                s1 += ((mm >> g1) & 1u) ? sd[t * K + k1] : 0.f;
            }
            acc0 += s0; acc1 += s1;
        }
        __syncthreads();   // before next tile overwrites LDS
    }

    // device-scope combine (coherent across XCDs)
    if (v0) atomicAdd(&sums[c0], acc0);
    if (v1) atomicAdd(&sums[c1], acc1);
    __syncthreads();   // gfx950: drains vmcnt(0) -> this block's atomics globally performed

    int* cnt = (int*)(sums + CNT_IDX);
    if (tid == 0) {
        const int done = __hip_atomic_fetch_add(cnt, 1, __ATOMIC_ACQ_REL,
                                                __HIP_MEMORY_SCOPE_AGENT);
        last_flag = (done == NBLK - 1) ? 1 : 0;
    }
    __syncthreads();
    if (!last_flag) return;

    // last block: agent-scope loads of the final sums, then first-index argmax
    for (int c = tid; c < KG; c += TPB)
        A[c] = __hip_atomic_load(&sums[c], __ATOMIC_ACQUIRE, __HIP_MEMORY_SCOPE_AGENT);
    __syncthreads();

    if (tid < K && G > 0) {
        const int base = tid * G;
        float bv = A[base];
        int bg = 0;
        for (int g = 1; g < G; ++g) {
            const float v = A[base + g];
            if (v > bv) { bv = v; bg = g; }   // strict '>' keeps first index on ties
        }
        out[tid] = bg;
    }
}

extern "C" void kernel_launch(void* const* d_in, const int* in_sizes, int n_in,
                              void* d_out, int out_size, void* d_ws, size_t ws_size,
                              hipStream_t stream) {
    const float* seg = (const float*)d_in[0];
    // d_in[1] (prob) does not affect the reference output
    const int* gt  = (const int*)d_in[2];
    const int* gpn = (const int*)d_in[3];

    const int N = in_sizes[1];              // prob is (N,1)
    const int K = in_sizes[0] / N;          // 21
    const int NT = (N + TPB - 1) / TPB;     // 1200 tiles

    int NBLK = 600;                         // 2 tiles/block; atomic depth 600 per cell
    if (NBLK > NT) NBLK = NT;
    if (NBLK < 1) NBLK = 1;

    // zero sums + counter every call (harness poisons d_ws once before timing)
    hipMemsetAsync(d_ws, 0, (CNT_IDX + 4) * sizeof(float), stream);

    msk_fused<<<NBLK, TPB, 0, stream>>>(seg, gt, gpn, (float*)d_ws, (int*)d_out,
                                        N, K, NT, NBLK);
}

// Round 3
// 71.393 us; speedup vs baseline: 1.2768x; 1.2768x over previous
//
#include <hip/hip_runtime.h>

#define EPSF 1e-6f
#define TPB 256
#define KMAX 24          // max segmentation channels supported (K=21 here)
#define RS (TPB + 4)     // transposed row stride in words (260, multiple of 4 for b128)
#define CELL_MAX 448     // >= K*G upper bound (21*21=441)
#define CNT_IDX 444      // int counter slot (float index) in d_ws

// Fused: A[k,g] = sum_n d[k,n]*gi[g,n], d = log2((s+eps)/(1-s+eps));
// argmin_g ce[k,g] == argmax_g A[k,g] (ce = -(A*ln2 + const_k)/N, scale-invariant).
// Cross-block combine via device-scope float atomics; last block does argmax.
__global__ __launch_bounds__(TPB) void msk_fused(
    const float* __restrict__ seg,   // (N, K) row-major
    const int* __restrict__ gt,      // (Gmax, N) row-major
    const int* __restrict__ gpn,     // scalar gt_plane_num
    float* __restrict__ sums,        // d_ws: [CELL_MAX] float sums, int counter at CNT_IDX
    int* __restrict__ out,           // (K,) int32 argmin indices
    int N, int K, int NT, int NBLK)
{
    const int G = *gpn;
    const int KG = K * G;
    const int tid = threadIdx.x;

    __shared__ float sd[KMAX * RS];      // raw seg tile (pixel-major), then d transposed [k][t]
    __shared__ unsigned m_lds[TPB];
    __shared__ float A[CELL_MAX];
    __shared__ int last_flag;

    // fixed cell assignment: thread owns cells tid and tid+TPB (KG <= 2*TPB)
    const int c0 = tid;
    const int c1 = tid + TPB;
    const bool v0 = (c0 < KG);
    const bool v1 = (c1 < KG);
    const int k0 = v0 ? (c0 / G) : 0;
    const int g0 = v0 ? (c0 - k0 * G) : 0;
    const int k1 = v1 ? (c1 / G) : 0;
    const int g1 = v1 ? (c1 - k1 * G) : 0;

    float acc0 = 0.f, acc1 = 0.f;
    const long long NK = (long long)N * K;
    const int TE = TPB * K;              // floats per tile (TPB*K % 4 == 0)

    for (int tile = blockIdx.x; tile < NT; tile += NBLK) {
        const long long pix0 = (long long)tile * TPB;
        const long long e0 = pix0 * K;

        // ---- stage seg tile, coalesced float4 ----
        if (pix0 + TPB <= N) {
            const float4* seg4 = reinterpret_cast<const float4*>(seg + e0);
            float4* sd4 = reinterpret_cast<float4*>(sd);
            const int TE4 = TE >> 2;
            for (int i = tid; i < TE4; i += TPB) sd4[i] = seg4[i];
        } else {
            for (int i = tid; i < TE; i += TPB) {
                const long long ge = e0 + i;
                sd[i] = (ge < NK) ? seg[ge] : 0.5f;    // masked out anyway
            }
        }

        // ---- GT mask bits for own pixel (coalesced per g) ----
        {
            const long long p = pix0 + tid;
            unsigned m = 0u;
            if (p < N) {
                for (int g = 0; g < G; ++g)
                    m |= (gt[(long long)g * N + p] != 0) ? (1u << g) : 0u;
            }
            m_lds[tid] = m;
        }
        __syncthreads();

        // ---- own-row log-odds into registers (stride-21 LDS reads: conflict-free) ----
        float dreg[KMAX];
        {
            const int b = tid * K;
            #pragma unroll
            for (int k = 0; k < KMAX; ++k) {
                if (k < K) {
                    const float s = sd[b + k];
                    dreg[k] = __log2f(s + EPSF) - __log2f(1.0f - s + EPSF);
                }
            }
        }
        __syncthreads();

        // ---- transposed write d[k][tid] (consecutive lanes -> consecutive words) ----
        #pragma unroll
        for (int k = 0; k < KMAX; ++k)
            if (k < K) sd[k * RS + tid] = dreg[k];
        __syncthreads();

        // ---- accumulate: 4 pixels per iter via b128; 4 indep partials per cell ----
        {
            const float4* dk0v = reinterpret_cast<const float4*>(sd + k0 * RS);
            const float4* dk1v = reinterpret_cast<const float4*>(sd + k1 * RS);
            const uint4* m4 = reinterpret_cast<const uint4*>(m_lds);
            float s00 = 0.f, s01 = 0.f, s02 = 0.f, s03 = 0.f;
            float s10 = 0.f, s11 = 0.f, s12 = 0.f, s13 = 0.f;
            #pragma unroll 4
            for (int t4 = 0; t4 < TPB / 4; ++t4) {
                const uint4 mm = m4[t4];               // same-address broadcast
                const float4 a = dk0v[t4];             // <=4 distinct addrs/wave
                const float4 b = dk1v[t4];
                s00 += ((mm.x >> g0) & 1u) ? a.x : 0.f;
                s01 += ((mm.y >> g0) & 1u) ? a.y : 0.f;
                s02 += ((mm.z >> g0) & 1u) ? a.z : 0.f;
                s03 += ((mm.w >> g0) & 1u) ? a.w : 0.f;
                s10 += ((mm.x >> g1) & 1u) ? b.x : 0.f;
                s11 += ((mm.y >> g1) & 1u) ? b.y : 0.f;
                s12 += ((mm.z >> g1) & 1u) ? b.z : 0.f;
                s13 += ((mm.w >> g1) & 1u) ? b.w : 0.f;
            }
            acc0 += (s00 + s01) + (s02 + s03);
            acc1 += (s10 + s11) + (s12 + s13);
        }
        __syncthreads();   // before next tile overwrites LDS
    }

    // ---- device-scope combine (coherent across XCDs) ----
    if (v0) atomicAdd(&sums[c0], acc0);
    if (v1) atomicAdd(&sums[c1], acc1);
    __syncthreads();   // drains vmcnt -> this block's atomics globally performed

    int* cnt = (int*)(sums + CNT_IDX);
    if (tid == 0) {
        const int done = __hip_atomic_fetch_add(cnt, 1, __ATOMIC_ACQ_REL,
                                                __HIP_MEMORY_SCOPE_AGENT);
        last_flag = (done == NBLK - 1) ? 1 : 0;
    }
    __syncthreads();
    if (!last_flag) return;

    // ---- last block: agent-scope loads of final sums, first-index argmax ----
    for (int c = tid; c < KG; c += TPB)
        A[c] = __hip_atomic_load(&sums[c], __ATOMIC_ACQUIRE, __HIP_MEMORY_SCOPE_AGENT);
    __syncthreads();

    if (tid < K && G > 0) {
        const int base = tid * G;
        float bv = A[base];
        int bg = 0;
        for (int g = 1; g < G; ++g) {
            const float v = A[base + g];
            if (v > bv) { bv = v; bg = g; }   // strict '>' keeps first index on ties
        }
        out[tid] = bg;
    }
}

extern "C" void kernel_launch(void* const* d_in, const int* in_sizes, int n_in,
                              void* d_out, int out_size, void* d_ws, size_t ws_size,
                              hipStream_t stream) {
    const float* seg = (const float*)d_in[0];
    // d_in[1] (prob) does not affect the reference output
    const int* gt  = (const int*)d_in[2];
    const int* gpn = (const int*)d_in[3];

    const int N = in_sizes[1];              // prob is (N,1)
    const int K = in_sizes[0] / N;          // 21
    const int NT = (N + TPB - 1) / TPB;     // 1200 tiles

    int NBLK = NT;                          // 1 tile per block
    if (NBLK > 1200) NBLK = 1200;
    if (NBLK < 1) NBLK = 1;

    // zero sums + counter every call (harness poisons d_ws once before timing)
    hipMemsetAsync(d_ws, 0, (CNT_IDX + 4) * sizeof(float), stream);

    msk_fused<<<NBLK, TPB, 0, stream>>>(seg, gt, gpn, (float*)d_ws, (int*)d_out,
                                        N, K, NT, NBLK);
}

// Round 4
// 58.460 us; speedup vs baseline: 1.5593x; 1.2212x over previous
//
#include <hip/hip_runtime.h>

#define EPSF 1e-6f
#define TPB 256
#define KMAXC 21         // max K supported (K = 21 here)
#define NG 21            // per-k accumulator slots (>= max G)
#define RS 260           // d row stride in words (multiple of 4 -> 16B aligned rows)
#define CN 12            // pixel-chunks per tile (K*CN = 252 <= TPB)
#define CELL_MAX 448
#define CNT_IDX 444      // int counter slot (float index) in d_ws

typedef float f32x4 __attribute__((ext_vector_type(4), aligned(4)));

// chunk c covers 4-pixel groups [T4S(c), T4S(c+1)) of the 256-pixel tile
__device__ __forceinline__ int T4S(int c) { return (((64 * c) / 3) & ~3) >> 2; }

// masked accumulate: sg[g] += bit_g(MB) ? DV : 0   (bitwise select: bfe_i32+and+add)
#define MAC1(DV, MB) do {                                       \
    const float dvv_ = (DV);                                    \
    const int   mbi_ = (int)(MB);                               \
    _Pragma("unroll")                                           \
    for (int g = 0; g < NG; ++g) {                              \
      const int sel_ = (mbi_ << (31 - g)) >> 31;                \
      sg[g] += __int_as_float(__float_as_int(dvv_) & sel_);     \
    }                                                           \
  } while (0)

// A[k,g] = sum_n d[k,n]*gi[g,n], d = log2((s+eps)/(1-s+eps));
// argmin_g ce[k,g] == argmax_g A[k,g] (ce = -(A*ln2 + const_k)/N).
__global__ __launch_bounds__(TPB) void msk_fused(
    const float* __restrict__ seg,   // (N, K) row-major
    const int* __restrict__ gt,      // (Gmax, N) row-major
    const int* __restrict__ gpn,     // scalar gt_plane_num
    float* __restrict__ sums,        // d_ws: [CELL_MAX] floats + int counter at CNT_IDX
    int* __restrict__ out,           // (K,) int32 argmin indices
    int N, int K, int NT, int NBLK)
{
    const int G = *gpn;
    const int tid = threadIdx.x;

    __shared__ __align__(16) float sd[KMAXC * RS];   // d rows [k][t]; later: partials
    __shared__ __align__(16) unsigned m_lds[TPB];
    __shared__ int last_flag;

    // accum ownership: thread (k, c) accumulates NG per-g sums over chunk c
    const bool act = (tid < K * CN);
    const int k = act ? (tid / CN) : 0;
    const int c = act ? (tid - k * CN) : 0;
    const int t4s = T4S(c);
    const int t4e = T4S(c + 1);

    float sg[NG];
    #pragma unroll
    for (int g = 0; g < NG; ++g) sg[g] = 0.f;

    for (int tile = blockIdx.x; tile < NT; tile += NBLK) {
        const int pix0 = tile * TPB;
        const int p = pix0 + tid;

        __syncthreads();   // previous tile's accum reads done before overwrite

        // ---- stage: own pixel's log-odds row -> sd (k-major), mask bits -> m_lds ----
        if (p < N) {
            float dreg[KMAXC];
            if (K == KMAXC) {
                const f32x4* r4 = (const f32x4*)(seg + (size_t)p * KMAXC);
                const f32x4 a = r4[0], b = r4[1], cc = r4[2], dd = r4[3], e = r4[4];
                const float last = seg[(size_t)p * KMAXC + 20];
                dreg[0]=a.x;  dreg[1]=a.y;  dreg[2]=a.z;  dreg[3]=a.w;
                dreg[4]=b.x;  dreg[5]=b.y;  dreg[6]=b.z;  dreg[7]=b.w;
                dreg[8]=cc.x; dreg[9]=cc.y; dreg[10]=cc.z;dreg[11]=cc.w;
                dreg[12]=dd.x;dreg[13]=dd.y;dreg[14]=dd.z;dreg[15]=dd.w;
                dreg[16]=e.x; dreg[17]=e.y; dreg[18]=e.z; dreg[19]=e.w;
                dreg[20]=last;
            } else {
                #pragma unroll
                for (int kk = 0; kk < KMAXC; ++kk)
                    dreg[kk] = (kk < K) ? seg[(size_t)p * K + kk] : 0.5f;
            }
            unsigned m = 0u;
            for (int g = 0; g < G; ++g)
                m |= (gt[(size_t)g * N + p] != 0) ? (1u << g) : 0u;
            m_lds[tid] = m;
            #pragma unroll
            for (int kk = 0; kk < KMAXC; ++kk) {
                if (kk < K) {
                    const float s = dreg[kk];
                    sd[kk * RS + tid] = __log2f(s + EPSF) - __log2f(1.0f - s + EPSF);
                }
            }
        } else {
            m_lds[tid] = 0u;   // mask=0 nullifies any stale d
        }
        __syncthreads();

        // ---- accumulate: stream own k-row; 21 reg accumulators; 3 VALU/MAC ----
        if (act) {
            const f32x4* dk4 = (const f32x4*)(sd + k * RS);
            const uint4*  m4 = (const uint4*)m_lds;
            for (int t4 = t4s; t4 < t4e; ++t4) {
                const uint4 mm = m4[t4];
                const f32x4 dv = dk4[t4];
                MAC1(dv.x, mm.x);
                MAC1(dv.y, mm.y);
                MAC1(dv.z, mm.z);
                MAC1(dv.w, mm.w);
            }
        }
    }

    // ---- cross-chunk reduce via LDS partial table (reuses sd) ----
    __syncthreads();
    if (act) {
        #pragma unroll
        for (int g = 0; g < NG; ++g)
            sd[(k * NG + g) * CN + c] = sg[g];
    }
    __syncthreads();

    const int KGC = K * NG;
    for (int cell = tid; cell < KGC; cell += TPB) {
        const f32x4* pr = (const f32x4*)(sd + cell * CN);
        const f32x4 a = pr[0], b = pr[1], cc = pr[2];
        const float v = ((a.x + a.y) + (a.z + a.w))
                      + ((b.x + b.y) + (b.z + b.w))
                      + ((cc.x + cc.y) + (cc.z + cc.w));
        atomicAdd(&sums[cell], v);   // device-scope, coherent across XCDs
    }
    __syncthreads();   // drains vmcnt -> this block's atomics globally performed

    int* cnt = (int*)(sums + CNT_IDX);
    if (tid == 0) {
        const int done = __hip_atomic_fetch_add(cnt, 1, __ATOMIC_ACQ_REL,
                                                __HIP_MEMORY_SCOPE_AGENT);
        last_flag = (done == NBLK - 1) ? 1 : 0;
    }
    __syncthreads();
    if (!last_flag) return;

    // ---- last block: load final sums, first-index argmax per k ----
    float* A = sd;
    for (int cell = tid; cell < KGC; cell += TPB)
        A[cell] = __hip_atomic_load(&sums[cell], __ATOMIC_ACQUIRE,
                                    __HIP_MEMORY_SCOPE_AGENT);
    __syncthreads();

    if (tid < K) {
        const int base = tid * NG;
        float bv; int bg = 0;
        if (G > 0) {
            bv = A[base];
            for (int g = 1; g < G; ++g) {
                const float v = A[base + g];
                if (v > bv) { bv = v; bg = g; }   // strict '>' keeps first index
            }
        }
        out[tid] = bg;
    }
}

extern "C" void kernel_launch(void* const* d_in, const int* in_sizes, int n_in,
                              void* d_out, int out_size, void* d_ws, size_t ws_size,
                              hipStream_t stream) {
    const float* seg = (const float*)d_in[0];
    // d_in[1] (prob) does not affect the reference output
    const int* gt  = (const int*)d_in[2];
    const int* gpn = (const int*)d_in[3];

    const int N = in_sizes[1];              // prob is (N,1)
    const int K = in_sizes[0] / N;          // 21
    const int NT = (N + TPB - 1) / TPB;     // 1200 tiles

    int NBLK = 600;                         // 2 tiles/block, all co-resident
    if (NBLK > NT) NBLK = NT;
    if (NBLK < 1) NBLK = 1;

    // zero sums + counter every call (harness poisons d_ws once before timing)
    hipMemsetAsync(d_ws, 0, CELL_MAX * sizeof(float), stream);

    msk_fused<<<NBLK, TPB, 0, stream>>>(seg, gt, gpn, (float*)d_ws, (int*)d_out,
                                        N, K, NT, NBLK);
}

// Round 5
// 48.933 us; speedup vs baseline: 1.8629x; 1.1947x over previous
//
#include <hip/hip_runtime.h>

#define EPSF 1e-6f
#define TPB 256
#define KMAXC 21         // max K supported (K = 21 here)
#define NG 21            // per-k accumulator slots (>= max G)
#define RS 260           // d row stride in words (multiple of 4 -> 16B aligned rows)
#define CN 12            // pixel-chunks per tile (K*CN = 252 <= TPB)
#define TBL 448          // floats per replica sum table
#define NREP 8           // replicated atomic tables (spread L3 contention)
#define CNT_OFF (TBL * NREP)   // float index of the int counter in d_ws

typedef float f32x4 __attribute__((ext_vector_type(4), aligned(4)));

// chunk c covers 4-pixel groups [T4S(c), T4S(c+1)) of the 256-pixel tile
__device__ __forceinline__ int T4S(int c) { return (((64 * c) / 3) & ~3) >> 2; }

// masked accumulate: sg[g] += bit_g(MB) ? DV : 0  (sbfe+and+add = 3 VALU)
#define MAC1(DV, MB) do {                                       \
    const float dvv_ = (DV);                                    \
    const int   mbi_ = (int)(MB);                               \
    _Pragma("unroll")                                           \
    for (int g = 0; g < NG; ++g) {                              \
      const int sel_ = __builtin_amdgcn_sbfe(mbi_, g, 1);       \
      sg[g] += __int_as_float(__float_as_int(dvv_) & sel_);     \
    }                                                           \
  } while (0)

// A[k,g] = sum_n d[k,n]*gi[g,n], d = log2((s+eps)/(1-s+eps));
// argmin_g ce[k,g] == argmax_g A[k,g] (ce = -(A*ln2 + const_k)/N).
__global__ __launch_bounds__(TPB) void msk_fused(
    const float* __restrict__ seg,   // (N, K) row-major
    const int* __restrict__ gt,      // (GROWS, N) row-major
    const int* __restrict__ gpn,     // scalar gt_plane_num
    float* __restrict__ sums,        // d_ws: NREP*[TBL] floats + int counter at CNT_OFF
    int* __restrict__ out,           // (K,) int32 argmin indices
    int N, int K, int GROWS, int NT, int NBLK)
{
    const int G = *gpn;
    const unsigned lowmask = (G >= 32) ? 0xFFFFFFFFu
                                       : ((G <= 0) ? 0u : ((1u << G) - 1u));
    const int tid = threadIdx.x;

    __shared__ __align__(16) float sd[KMAXC * RS];   // d rows [k][t]; later: partials
    __shared__ __align__(16) unsigned m_lds[TPB];
    __shared__ int last_flag;

    // accum ownership: thread (k, c) accumulates NG per-g sums over chunk c
    const bool act = (tid < K * CN);
    const int k = act ? (tid / CN) : 0;
    const int c = act ? (tid - k * CN) : 0;
    const int t4s = T4S(c);
    const int t4e = T4S(c + 1);

    float sg[NG];
    #pragma unroll
    for (int g = 0; g < NG; ++g) sg[g] = 0.f;

    for (int tile = blockIdx.x; tile < NT; tile += NBLK) {
        const int pix0 = tile * TPB;
        const int p = pix0 + tid;

        __syncthreads();   // previous tile's accum reads done before overwrite

        // ---- stage: own pixel's log-odds row -> sd (k-major), mask bits -> m_lds ----
        if (p < N) {
            float dreg[KMAXC];
            if (K == KMAXC) {
                const f32x4* r4 = (const f32x4*)(seg + (size_t)p * KMAXC);
                const f32x4 a = r4[0], b = r4[1], cc = r4[2], dd = r4[3], e = r4[4];
                const float last = seg[(size_t)p * KMAXC + 20];
                dreg[0]=a.x;  dreg[1]=a.y;  dreg[2]=a.z;  dreg[3]=a.w;
                dreg[4]=b.x;  dreg[5]=b.y;  dreg[6]=b.z;  dreg[7]=b.w;
                dreg[8]=cc.x; dreg[9]=cc.y; dreg[10]=cc.z;dreg[11]=cc.w;
                dreg[12]=dd.x;dreg[13]=dd.y;dreg[14]=dd.z;dreg[15]=dd.w;
                dreg[16]=e.x; dreg[17]=e.y; dreg[18]=e.z; dreg[19]=e.w;
                dreg[20]=last;
            } else {
                #pragma unroll
                for (int kk = 0; kk < KMAXC; ++kk)
                    dreg[kk] = (kk < K) ? seg[(size_t)p * K + kk] : 0.5f;
            }
            // fully-unrolled independent gt loads (clamped row idx, no branches),
            // then keep only the first G bits
            unsigned m = 0u;
            #pragma unroll
            for (int g = 0; g < NG; ++g) {
                const int gg = (g < GROWS) ? g : (GROWS - 1);
                m |= (gt[(size_t)gg * N + p] != 0) ? (1u << g) : 0u;
            }
            m_lds[tid] = m & lowmask;
            #pragma unroll
            for (int kk = 0; kk < KMAXC; ++kk) {
                if (kk < K) {
                    const float s = dreg[kk];
                    sd[kk * RS + tid] = __log2f(s + EPSF) - __log2f(1.0f - s + EPSF);
                }
            }
        } else {
            m_lds[tid] = 0u;   // mask=0 nullifies any stale d (bitwise select -> +0.0)
        }
        __syncthreads();

        // ---- accumulate: stream own k-row; 21 reg accumulators; 3 VALU/MAC ----
        if (act) {
            const f32x4* dk4 = (const f32x4*)(sd + k * RS);
            const uint4*  m4 = (const uint4*)m_lds;
            for (int t4 = t4s; t4 < t4e; ++t4) {
                const uint4 mm = m4[t4];
                const f32x4 dv = dk4[t4];
                MAC1(dv.x, mm.x);
                MAC1(dv.y, mm.y);
                MAC1(dv.z, mm.z);
                MAC1(dv.w, mm.w);
            }
        }
    }

    // ---- cross-chunk reduce via LDS partial table (reuses sd) ----
    __syncthreads();
    if (act) {
        #pragma unroll
        for (int g = 0; g < NG; ++g)
            sd[(k * NG + g) * CN + c] = sg[g];
    }
    __syncthreads();

    const int KGC = K * NG;
    float* stbl = sums + (size_t)(blockIdx.x & (NREP - 1)) * TBL;
    for (int cell = tid; cell < KGC; cell += TPB) {
        const f32x4* pr = (const f32x4*)(sd + cell * CN);
        const f32x4 a = pr[0], b = pr[1], cc = pr[2];
        const float v = ((a.x + a.y) + (a.z + a.w))
                      + ((b.x + b.y) + (b.z + b.w))
                      + ((cc.x + cc.y) + (cc.z + cc.w));
        atomicAdd(&stbl[cell], v);   // device-scope, coherent across XCDs
    }
    __syncthreads();   // drains vmcnt -> this block's atomics globally performed

    int* cnt = (int*)(sums + CNT_OFF);
    if (tid == 0) {
        const int done = __hip_atomic_fetch_add(cnt, 1, __ATOMIC_ACQ_REL,
                                                __HIP_MEMORY_SCOPE_AGENT);
        last_flag = (done == NBLK - 1) ? 1 : 0;
    }
    __syncthreads();
    if (!last_flag) return;

    // ---- last block: sum replica tables, first-index argmax per k ----
    float* A = sd;
    for (int cell = tid; cell < KGC; cell += TPB) {
        float v = 0.f;
        #pragma unroll
        for (int r = 0; r < NREP; ++r)
            v += __hip_atomic_load(&sums[(size_t)r * TBL + cell], __ATOMIC_ACQUIRE,
                                   __HIP_MEMORY_SCOPE_AGENT);
        A[cell] = v;
    }
    __syncthreads();

    if (tid < K) {
        const int base = tid * NG;
        float bv; int bg = 0;
        const int GG = (G < NG) ? G : NG;
        if (GG > 0) {
            bv = A[base];
            for (int g = 1; g < GG; ++g) {
                const float v = A[base + g];
                if (v > bv) { bv = v; bg = g; }   // strict '>' keeps first index
            }
        }
        out[tid] = bg;
    }
}

extern "C" void kernel_launch(void* const* d_in, const int* in_sizes, int n_in,
                              void* d_out, int out_size, void* d_ws, size_t ws_size,
                              hipStream_t stream) {
    const float* seg = (const float*)d_in[0];
    // d_in[1] (prob) does not affect the reference output
    const int* gt  = (const int*)d_in[2];
    const int* gpn = (const int*)d_in[3];

    const int N = in_sizes[1];              // prob is (N,1)
    const int K = in_sizes[0] / N;          // 21
    const int GROWS = in_sizes[2] / N;      // 21 gt rows available
    const int NT = (N + TPB - 1) / TPB;     // 1200 tiles

    int NBLK = NT;                          // 1 tile per block
    if (NBLK > 2048) NBLK = 2048;
    if (NBLK < 1) NBLK = 1;

    // zero replica tables + counter every call
    hipMemsetAsync(d_ws, 0, CNT_OFF * sizeof(float) + 16, stream);

    msk_fused<<<NBLK, TPB, 0, stream>>>(seg, gt, gpn, (float*)d_ws, (int*)d_out,
                                        N, K, GROWS, NT, NBLK);
}